// Round 2
// baseline (588.982 us; speedup 1.0000x reference)
//
#include <hip/hip_runtime.h>
#include <hip/hip_fp8.h>
#include <cstdint>
#include <cmath>

// Problem constants
#define B_   4
#define C_   512
#define HW_  4096
#define G_   32
#define CPG_ 16
#define EPS_ 1e-6f
#define SCALE_ 0.04419417382415922f  // 1/sqrt(512)
#define PSCALE_ 0.0625f              // P pre-scale; cancels in acc/rowsum ratio

// ---------------------------------------------------------------------------
// Column permutation (sigma): GEMM epilogues store outputs in the MFMA
// C-layout packed order. Within each 64-col group, stored position
// p = fr*4 + j holds true column c = j*16 + fr. Invariant under contraction
// as long as producer & consumer agree.
//
// Weight scaling: fp8 weights are stored x16; the MFMA e8m0 scale operand
// 0x7B (= 2^-4) folds the 1/16 back in HW. Same trick for hmT8.
//
// R10 change (post-mortem of R9's 164 us fused kernel): the fused kernel had
// 136 KB LDS -> 1 block/CU -> 8 lockstep waves with nothing to hide stalls.
// Now: 32-row Q panels, 512 blocks, SINGLE-buffered K (64 KB) + 4 KB P =
// 68 KB LDS -> 2 independent blocks/CU. K(t+1) stage issues right after the
// P-visible barrier (K buffer provably free) and flies during PV(t).
// ---------------------------------------------------------------------------

typedef __bf16 bf16_t;
typedef __bf16 bf16x8 __attribute__((ext_vector_type(8)));
typedef float  f32x4  __attribute__((ext_vector_type(4)));
typedef int    i32x4  __attribute__((ext_vector_type(4)));
typedef int    i32x8  __attribute__((ext_vector_type(8)));
typedef unsigned int u32;
typedef __hip_fp8_e4m3 fp8_t;  // OCP e4m3fn on gfx950

// Async global->LDS copy, 16B per lane. LDS dest is wave-uniform base + lane*16.
__device__ __forceinline__ void cp16(const void* g, void* l) {
  __builtin_amdgcn_global_load_lds((__attribute__((address_space(1))) u32*)(g),
                                   (__attribute__((address_space(3))) u32*)(l),
                                   16, 0, 0);
}

__device__ __forceinline__ void zero_acc(f32x4 acc[4][4]) {
  f32x4 z = {0.f, 0.f, 0.f, 0.f};
#pragma unroll
  for (int i = 0; i < 4; ++i)
#pragma unroll
    for (int j = 0; j < 4; ++j) acc[i][j] = z;
}

// MX-fp8 BT GEMM mainloop (BK=128): mfma_scale_f32_16x16x128_f8f6f4, fmt 0
// (e4m3), per-operand e8m0 scales SA/SB (0x7F = 1.0, 0x7B = 2^-4).
// Used by the small square GEMMs (qkv / v / proj).
template <bool ROWSUM, int SA = 0x7F, int SB = 0x7F>
__device__ __forceinline__ void gemm_bt_mx(const unsigned char* __restrict__ A,
                                           const unsigned char* __restrict__ B,
                                           int K, int lda, int ldb,
                                           f32x4 acc[4][4], f32x4 accl[4]) {
  __shared__ __align__(16) unsigned char As[128 * 128];
  __shared__ __align__(16) unsigned char Bs[128 * 128];
  const int tid  = threadIdx.x;
  const int wave = tid >> 6;
  const int lane = tid & 63;
  const int wm = (wave >> 1) * 64;
  const int wn = (wave & 1) * 64;
  const int srow = lane >> 3;
  const int gch  = ((lane & 7) - srow) & 7;
  const unsigned char* gA = A + (size_t)(wave * 32 + srow) * lda + gch * 16;
  const unsigned char* gB = B + (size_t)(wave * 32 + srow) * ldb + gch * 16;
  unsigned char* lA = As + wave * 32 * 128;
  unsigned char* lB = Bs + wave * 32 * 128;
  const int fr = lane & 15;
  const int q  = lane >> 4;
  const int co0 = ((2 * q     + fr) & 7) * 16;
  const int co1 = ((2 * q + 1 + fr) & 7) * 16;
  const i32x8 vones = {0x38383838, 0x38383838, 0x38383838, 0x38383838,
                       0x38383838, 0x38383838, 0x38383838, 0x38383838};

  for (int k0 = 0; k0 < K; k0 += 128) {
#pragma unroll
    for (int cc = 0; cc < 4; ++cc) {
      cp16(gA + (size_t)(cc * 8) * lda, lA + cc * 1024);
      cp16(gB + (size_t)(cc * 8) * ldb, lB + cc * 1024);
    }
    gA += 128; gB += 128;
    __syncthreads();
    i32x8 a[4], b[4];
#pragma unroll
    for (int i = 0; i < 4; ++i) {
      const int ro = (wm + i * 16 + fr) * 128;
      i32x4 lo = *(const i32x4*)(As + ro + co0);
      i32x4 hi = *(const i32x4*)(As + ro + co1);
      a[i] = __builtin_shufflevector(lo, hi, 0, 1, 2, 3, 4, 5, 6, 7);
    }
#pragma unroll
    for (int j = 0; j < 4; ++j) {
      const int ro = (wn + j * 16 + fr) * 128;
      i32x4 lo = *(const i32x4*)(Bs + ro + co0);
      i32x4 hi = *(const i32x4*)(Bs + ro + co1);
      b[j] = __builtin_shufflevector(lo, hi, 0, 1, 2, 3, 4, 5, 6, 7);
    }
#pragma unroll
    for (int i = 0; i < 4; ++i) {
#pragma unroll
      for (int j = 0; j < 4; ++j)
        acc[i][j] = __builtin_amdgcn_mfma_scale_f32_16x16x128_f8f6f4(
            a[i], b[j], acc[i][j], 0, 0, 0, SA, 0, SB);
      if (ROWSUM)
        accl[i] = __builtin_amdgcn_mfma_scale_f32_16x16x128_f8f6f4(
            a[i], vones, accl[i], 0, 0, 0, SA, 0, 0x7F);
    }
    __syncthreads();
  }
}

// ---------------- small prep kernels ----------------

__global__ void __launch_bounds__(256) cast_w_kernel(const float* __restrict__ qkv_w,
                                                     const float* __restrict__ proj_w,
                                                     fp8_t* __restrict__ wqkv8,
                                                     fp8_t* __restrict__ wproj8) {
  const int idx = blockIdx.x * 256 + threadIdx.x;   // quad index
  const int t = idx * 4;
  const int nq = 1536 * 512;
  if (t < nq) {
    u32 dw = 0;
    dw = (u32)__builtin_amdgcn_cvt_pk_fp8_f32(qkv_w[t] * 16.f, qkv_w[t + 1] * 16.f, (int)dw, false);
    dw = (u32)__builtin_amdgcn_cvt_pk_fp8_f32(qkv_w[t + 2] * 16.f, qkv_w[t + 3] * 16.f, (int)dw, true);
    *(u32*)((unsigned char*)wqkv8 + t) = dw;
  } else {
    const int tt = t - nq;          // o*512 + p, p multiple of 4
    const int o = tt >> 9;
    const int p = tt & 511;
    float v[4];
#pragma unroll
    for (int e = 0; e < 4; ++e) {
      const int pe = p + e;
      const int off = pe & 63;
      const int c = (pe & ~63) + ((off & 3) << 4) + (off >> 2);  // sigma(pe)
      v[e] = proj_w[(o << 9) + c] * 16.f;
    }
    u32 dw = 0;
    dw = (u32)__builtin_amdgcn_cvt_pk_fp8_f32(v[0], v[1], (int)dw, false);
    dw = (u32)__builtin_amdgcn_cvt_pk_fp8_f32(v[2], v[3], (int)dw, true);
    *(u32*)((unsigned char*)wproj8 + tt) = dw;
  }
}

__global__ void __launch_bounds__(256) gn_partial_kernel(const float* __restrict__ x,
                                                         float* __restrict__ stats) {
  __shared__ float rs[256], rss[256];
  const int bg = blockIdx.x >> 3;       // group id 0..127
  const int ch = blockIdx.x & 7;        // hw chunk 0..7
  const float4* base = (const float4*)(x + (size_t)bg * (CPG_ * HW_)) +
                       (size_t)ch * (CPG_ * HW_ / 4 / 8);
  float s = 0.f, ss = 0.f;
  for (int i = threadIdx.x; i < CPG_ * HW_ / 4 / 8; i += 256) {
    float4 v = base[i];
    s  += v.x + v.y + v.z + v.w;
    ss += v.x * v.x + v.y * v.y + v.z * v.z + v.w * v.w;
  }
  rs[threadIdx.x] = s; rss[threadIdx.x] = ss;
  __syncthreads();
  for (int st = 128; st > 0; st >>= 1) {
    if ((int)threadIdx.x < st) {
      rs[threadIdx.x]  += rs[threadIdx.x + st];
      rss[threadIdx.x] += rss[threadIdx.x + st];
    }
    __syncthreads();
  }
  if (threadIdx.x == 0) {
    atomicAdd(&stats[bg * 2 + 0], rs[0]);
    atomicAdd(&stats[bg * 2 + 1], rss[0]);
  }
}

__global__ void __launch_bounds__(256) norm_tr_kernel(const float* __restrict__ x,
                                                      const float* __restrict__ stats,
                                                      const float* __restrict__ nw,
                                                      const float* __restrict__ nb,
                                                      fp8_t* __restrict__ xnT8) {
  __shared__ float tile[64][65];   // [c_off][i_off]
  const int b  = blockIdx.z;
  const int i0 = blockIdx.x * 64;   // hw
  const int c0 = blockIdx.y * 64;   // channel
  const int tx = threadIdx.x & 63;
  const int ty = threadIdx.x >> 6;  // 0..3
  const int cbase = c0 + ty * 16;
  const int g = cbase >> 4;
  const float inv = 1.f / (float)(CPG_ * HW_);
  const float sum  = stats[(b * G_ + g) * 2 + 0];
  const float ssum = stats[(b * G_ + g) * 2 + 1];
  const float mean = sum * inv;
  const float rstd = rsqrtf(ssum * inv - mean * mean + EPS_);
#pragma unroll
  for (int r = 0; r < 16; ++r) {
    const int c = cbase + r;
    float v = x[((size_t)b * C_ + c) * HW_ + i0 + tx];
    tile[ty * 16 + r][tx] = (v - mean) * rstd * nw[c] + nb[c];
  }
  __syncthreads();
  const int il = threadIdx.x >> 2;
  const int q4 = threadIdx.x & 3;
#pragma unroll
  for (int m = 0; m < 4; ++m) {
    const int cq = q4 + m * 4;     // 0..15
    u32 dw = 0;
    dw = (u32)__builtin_amdgcn_cvt_pk_fp8_f32(tile[cq * 4 + 0][il], tile[cq * 4 + 1][il], (int)dw, false);
    dw = (u32)__builtin_amdgcn_cvt_pk_fp8_f32(tile[cq * 4 + 2][il], tile[cq * 4 + 3][il], (int)dw, true);
    *(u32*)((unsigned char*)xnT8 + ((size_t)b * HW_ + i0 + il) * C_ + c0 + cq * 4) = dw;
  }
}

// ---------------- GEMM kernels ----------------

__global__ void __launch_bounds__(256) qk_gemm_kernel(const fp8_t* __restrict__ xnT8,
                                                      const fp8_t* __restrict__ wqkv8,
                                                      const float* __restrict__ qkv_b,
                                                      fp8_t* __restrict__ QKt8) {
  const int b = blockIdx.z;
  f32x4 acc[4][4]; zero_acc(acc);
  const unsigned char* A  = (const unsigned char*)xnT8 + ((size_t)b * HW_ + blockIdx.y * 128) * C_;
  const unsigned char* Bp = (const unsigned char*)wqkv8 + (size_t)blockIdx.x * 128 * C_;
  gemm_bt_mx<false, 0x7F, 0x7B>(A, Bp, C_, C_, C_, acc, nullptr);
  const int lane = threadIdx.x & 63, wave = threadIdx.x >> 6;
  const int wm = (wave >> 1) * 64, wn = (wave & 1) * 64;
  const int fr = lane & 15, q = lane >> 4;
  const int r0 = blockIdx.y * 128 + wm + (q << 2);
  const int cb = blockIdx.x * 128 + wn;
  float bias[4];
#pragma unroll
  for (int j = 0; j < 4; ++j) bias[j] = qkv_b[cb + fr + j * 16];
#pragma unroll
  for (int i = 0; i < 4; ++i)
#pragma unroll
    for (int r = 0; r < 4; ++r) {
      const int row = r0 + i * 16 + r;
      u32 dw = 0;
      dw = (u32)__builtin_amdgcn_cvt_pk_fp8_f32(acc[i][0][r] + bias[0],
                                                acc[i][1][r] + bias[1], (int)dw, false);
      dw = (u32)__builtin_amdgcn_cvt_pk_fp8_f32(acc[i][2][r] + bias[2],
                                                acc[i][3][r] + bias[3], (int)dw, true);
      *(u32*)((unsigned char*)QKt8 + ((size_t)b * HW_ + row) * 1024 + cb + fr * 4) = dw;
    }
}

__global__ void __launch_bounds__(256) v_gemm_kernel(const fp8_t* __restrict__ wqkv8,
                                                     const fp8_t* __restrict__ xnT8,
                                                     const float* __restrict__ qkv_b,
                                                     fp8_t* __restrict__ V8) {
  const int b = blockIdx.z;
  f32x4 acc[4][4]; zero_acc(acc);
  const unsigned char* A  = (const unsigned char*)wqkv8 + (size_t)(1024 + blockIdx.y * 128) * C_;
  const unsigned char* Bp = (const unsigned char*)xnT8 + ((size_t)b * HW_ + blockIdx.x * 128) * C_;
  gemm_bt_mx<false, 0x7B, 0x7F>(A, Bp, C_, C_, C_, acc, nullptr);
  const int lane = threadIdx.x & 63, wave = threadIdx.x >> 6;
  const int wm = (wave >> 1) * 64, wn = (wave & 1) * 64;
  const int fr = lane & 15, q = lane >> 4;
  const int r0 = blockIdx.y * 128 + wm + (q << 2);
  const int cb = blockIdx.x * 128 + wn;
#pragma unroll
  for (int i = 0; i < 4; ++i)
#pragma unroll
    for (int r = 0; r < 4; ++r) {
      const int row = r0 + i * 16 + r;        // c channel (row of V8)
      const float bias = qkv_b[1024 + row];
      u32 dw = 0;
      dw = (u32)__builtin_amdgcn_cvt_pk_fp8_f32(acc[i][0][r] + bias,
                                                acc[i][1][r] + bias, (int)dw, false);
      dw = (u32)__builtin_amdgcn_cvt_pk_fp8_f32(acc[i][2][r] + bias,
                                                acc[i][3][r] + bias, (int)dw, true);
      *(u32*)((unsigned char*)V8 + ((size_t)b * C_ + row) * HW_ + cb + fr * 4) = dw;
    }
}

// ---------------------------------------------------------------------------
// Fused attention: S = exp(scale*QK^T) and H = (S.V)/rowsum(S), flash-style.
// Grid: 512 blocks = 4 batches x 128 Q-panels (32 rows), 512 threads (8 waves).
// LDS = 64 KB K panel (SINGLE buffer) + 4 KB P = 68 KB -> 2 blocks/CU; the
// two co-resident blocks are unsynchronized, so one block's MFMA bursts hide
// the other's barriers/exp/V-latency.
//   wave w: ih = w&1 -> 16-row half; jq = w>>1 -> S col quarter (32 of 128),
//           also PV channel group (128 of 512).
// Iteration t (32 panels of 128 j):
//   [vmcnt(0); barrier]  K(t) visible; P free
//   S: 8 MFMAs (Q regs x K LDS)  -> V early loads -> exp -> P LDS writes
//   [lgkmcnt(0); barrier] P(t) visible; K buffer free (all K reads drained)
//   stage K(t+1) (8 cp16)        <- flies during PV, consumed next top
//   PV: 9 MFMAs (P LDS x V global L2-hot, rolling)
// ---------------------------------------------------------------------------
__global__ void __launch_bounds__(512, 4)
fused_attn_kernel(const fp8_t* __restrict__ QKt8, const fp8_t* __restrict__ V8,
                  fp8_t* __restrict__ hmT8) {
  __shared__ __align__(16) unsigned char lds[65536 + 4096];
  unsigned char* plds = lds + 65536;

  // XCD-aware decode: batch b -> XCDs {2b, 2b+1}; 64 panels per XCD slot.
  const int n     = blockIdx.x;
  const int xcd   = n & 7;
  const int b     = xcd >> 1;
  const int panel = (xcd & 1) * 64 + (n >> 3);   // 0..127

  const int tid  = threadIdx.x;
  const int lane = tid & 63;
  const int wave = tid >> 6;
  const int fr   = lane & 15;
  const int q    = lane >> 4;
  const int ih   = wave & 1;
  const int jq   = wave >> 1;   // S col quarter; also PV channel group
  const int cg   = wave >> 1;

  const unsigned char* QKb = (const unsigned char*)QKt8 + (size_t)b * HW_ * 1024;
  const unsigned char* gK  = QKb + 512;   // K half of qkv columns

  const int sch = tid & 31;   // staging chunk within a 512-B row
  const int srw = tid >> 5;   // staging row within a 16-row pass

  // ---- prologue: stage Q (32x512) into K buffer, mod-32 rotation ----
#pragma unroll
  for (int p = 0; p < 2; ++p) {
    const int row = p * 16 + srw;
    cp16(QKb + (size_t)(panel * 32 + row) * 1024 + (((sch - row) & 31) << 4),
         lds + row * 512 + sch * 16);
  }
  asm volatile("s_waitcnt vmcnt(0)" ::: "memory");
  __builtin_amdgcn_s_barrier();

  // preload Q fragments: qf[k] covers rows ih*16, K-bytes k*128
  i32x8 qf[4];
  {
    const int row = ih * 16 + fr;
    const unsigned char* qr = lds + row * 512;
#pragma unroll
    for (int k = 0; k < 4; ++k) {
      i32x4 lo = *(const i32x4*)(qr + (((k * 8 + 2 * q + row) & 31) << 4));
      i32x4 hi = *(const i32x4*)(qr + (((k * 8 + 2 * q + 1 + row) & 31) << 4));
      qf[k] = __builtin_shufflevector(lo, hi, 0, 1, 2, 3, 4, 5, 6, 7);
    }
  }
  asm volatile("s_waitcnt lgkmcnt(0)" ::: "memory");
  __builtin_amdgcn_s_barrier();   // all waves done reading Q region

  // ---- stage K(0) ----
#pragma unroll
  for (int p = 0; p < 8; ++p) {
    const int row = p * 16 + srw;
    cp16(gK + (size_t)row * 1024 + (((sch - row) & 31) << 4),
         lds + row * 512 + sch * 16);
  }

  f32x4 pvacc[8];
  f32x4 accl;
  {
    f32x4 z = {0.f, 0.f, 0.f, 0.f};
#pragma unroll
    for (int j = 0; j < 8; ++j) pvacc[j] = z;
    accl = z;
  }
  const i32x8 vones = {0x38383838, 0x38383838, 0x38383838, 0x38383838,
                       0x38383838, 0x38383838, 0x38383838, 0x38383838};

  const unsigned char* vbase = (const unsigned char*)V8 +
      ((size_t)b * C_ + cg * 128 + fr) * HW_ + q * 32;

  const int kr0 = jq * 32 + fr;
  const int kr1 = kr0 + 16;
  const int offb = (jq >> 1) * 64 + fr * 4 + (jq & 1) * 2;  // P stored byte pos

#pragma unroll 1
  for (int t = 0; t < 32; ++t) {
    asm volatile("s_waitcnt vmcnt(0)" ::: "memory");  // K(t) resident
    __builtin_amdgcn_s_barrier();   // K(t) visible to all; P free for rewrite

    // ---- S phase: sacc[jj] over 4 K-steps (Q from regs, K from LDS) ----
    f32x4 sacc[2];
    {
      f32x4 z = {0.f, 0.f, 0.f, 0.f};
      sacc[0] = z; sacc[1] = z;
    }
    const unsigned char* k0p = lds + kr0 * 512;
    const unsigned char* k1p = lds + kr1 * 512;
    __builtin_amdgcn_s_setprio(1);
#pragma unroll
    for (int k = 0; k < 4; ++k) {
      i32x4 l0 = *(const i32x4*)(k0p + (((k * 8 + 2 * q + kr0) & 31) << 4));
      i32x4 h0 = *(const i32x4*)(k0p + (((k * 8 + 2 * q + 1 + kr0) & 31) << 4));
      i32x4 l1 = *(const i32x4*)(k1p + (((k * 8 + 2 * q + kr1) & 31) << 4));
      i32x4 h1 = *(const i32x4*)(k1p + (((k * 8 + 2 * q + 1 + kr1) & 31) << 4));
      i32x8 kf0 = __builtin_shufflevector(l0, h0, 0, 1, 2, 3, 4, 5, 6, 7);
      i32x8 kf1 = __builtin_shufflevector(l1, h1, 0, 1, 2, 3, 4, 5, 6, 7);
      sacc[0] = __builtin_amdgcn_mfma_scale_f32_16x16x128_f8f6f4(
          qf[k], kf0, sacc[0], 0, 0, 0, 0x7F, 0, 0x7F);
      sacc[1] = __builtin_amdgcn_mfma_scale_f32_16x16x128_f8f6f4(
          qf[k], kf1, sacc[1], 0, 0, 0, 0x7F, 0, 0x7F);
    }
    __builtin_amdgcn_s_setprio(0);

    // early V fragment loads (L2-hot) — issue before exp so latency hides
    const unsigned char* vp = vbase + t * 128;
    i32x4 vl[8], vh[8];
#pragma unroll
    for (int c = 0; c < 3; ++c) {
      vl[c] = *(const i32x4*)(vp + (size_t)(c * 16) * HW_);
      vh[c] = *(const i32x4*)(vp + (size_t)(c * 16) * HW_ + 16);
    }

    // ---- exp -> fp8 -> P LDS (b16 stores, sigma-packed, mod-8 rotation) ----
#pragma unroll
    for (int r = 0; r < 4; ++r) {
      const int row = ih * 16 + q * 4 + r;
      float e0 = __expf(sacc[0][r] * SCALE_) * PSCALE_;
      float e1 = __expf(sacc[1][r] * SCALE_) * PSCALE_;
      u32 dw = (u32)__builtin_amdgcn_cvt_pk_fp8_f32(e0, e1, 0, false);
      *(unsigned short*)(plds + row * 128 + ((((offb >> 4) + row) & 7) << 4) +
                         (offb & 15)) = (unsigned short)dw;
    }

    asm volatile("s_waitcnt lgkmcnt(0)" ::: "memory");  // own P writes done
    __builtin_amdgcn_s_barrier();                       // P(t) visible to all

    // stage K(t+1): K buffer free (all S(t) reads drained pre-barrier);
    // flies during PV(t), consumed at next loop top.
    if (t < 31) {
#pragma unroll
      for (int p = 0; p < 8; ++p) {
        const int row = p * 16 + srw;
        cp16(gK + (size_t)((t + 1) * 128 + row) * 1024 + (((sch - row) & 31) << 4),
             lds + row * 512 + sch * 16);
      }
    }

    // ---- PV phase: pa from P LDS, V rolling from global ----
    i32x8 pa;
    {
      const int prow = ih * 16 + fr;
      const unsigned char* pp = plds + prow * 128;
      i32x4 lo = *(const i32x4*)(pp + (((2 * q + prow) & 7) << 4));
      i32x4 hi = *(const i32x4*)(pp + (((2 * q + 1 + prow) & 7) << 4));
      pa = __builtin_shufflevector(lo, hi, 0, 1, 2, 3, 4, 5, 6, 7);
    }
    __builtin_amdgcn_s_setprio(1);
#pragma unroll
    for (int c = 0; c < 8; ++c) {
      if (c < 5) {
        vl[c + 3] = *(const i32x4*)(vp + (size_t)((c + 3) * 16) * HW_);
        vh[c + 3] = *(const i32x4*)(vp + (size_t)((c + 3) * 16) * HW_ + 16);
      }
      i32x8 v = __builtin_shufflevector(vl[c], vh[c], 0, 1, 2, 3, 4, 5, 6, 7);
      pvacc[c] = __builtin_amdgcn_mfma_scale_f32_16x16x128_f8f6f4(
          pa, v, pvacc[c], 0, 0, 0, 0x7F, 0, 0x7F);
    }
    accl = __builtin_amdgcn_mfma_scale_f32_16x16x128_f8f6f4(
        pa, vones, accl, 0, 0, 0, 0x7F, 0, 0x7F);
    __builtin_amdgcn_s_setprio(0);
  }

  // ---- epilogue: hmT8 = fp8(16 * pvacc / rowsum), sigma-packed channels ----
  unsigned char* hb = (unsigned char*)hmT8 + (size_t)b * HW_ * C_;
#pragma unroll
  for (int r = 0; r < 4; ++r) {
    const int row = panel * 32 + ih * 16 + q * 4 + r;
    const float rl = 16.f / accl[r];
#pragma unroll
    for (int g = 0; g < 2; ++g) {
      u32 dw = 0;
      dw = (u32)__builtin_amdgcn_cvt_pk_fp8_f32(pvacc[g * 4 + 0][r] * rl,
                                                pvacc[g * 4 + 1][r] * rl, (int)dw, false);
      dw = (u32)__builtin_amdgcn_cvt_pk_fp8_f32(pvacc[g * 4 + 2][r] * rl,
                                                pvacc[g * 4 + 3][r] * rl, (int)dw, true);
      *(u32*)(hb + (size_t)row * C_ + cg * 128 + g * 64 + fr * 4) = dw;
    }
  }
}

// out[b][o][i] = x[b][o][i] + proj_b[o] + (wproj8*2^-4)(sigma) . (hmT8*2^-4)(sigma)
__global__ void __launch_bounds__(256) proj_gemm_kernel(const fp8_t* __restrict__ wproj8,
                                                        const fp8_t* __restrict__ hmT8,
                                                        const float* __restrict__ proj_b,
                                                        const float* __restrict__ x,
                                                        float* __restrict__ out) {
  const int b = blockIdx.z;
  f32x4 acc[4][4]; zero_acc(acc);
  const unsigned char* A  = (const unsigned char*)wproj8 + (size_t)blockIdx.y * 128 * C_;
  const unsigned char* Bp = (const unsigned char*)hmT8 + ((size_t)b * HW_ + blockIdx.x * 128) * C_;
  gemm_bt_mx<false, 0x7B, 0x7B>(A, Bp, C_, C_, C_, acc, nullptr);
  const int lane = threadIdx.x & 63, wave = threadIdx.x >> 6;
  const int wm = (wave >> 1) * 64, wn = (wave & 1) * 64;
  const int r0 = blockIdx.y * 128 + wm + ((lane >> 4) << 2);
  const int c0 = blockIdx.x * 128 + wn + (lane & 15);
#pragma unroll
  for (int i = 0; i < 4; ++i)
#pragma unroll
    for (int r = 0; r < 4; ++r) {
      const int row = r0 + i * 16 + r;
      const float bias = proj_b[row];
#pragma unroll
      for (int j = 0; j < 4; ++j) {
        const int col = c0 + j * 16;
        const size_t idx = ((size_t)b * C_ + row) * HW_ + col;
        out[idx] = x[idx] + bias + acc[i][j][r];
      }
    }
}

// ---------------- launch ----------------
// Workspace layout (bytes), total ~43 MB (P8 not materialized):
//   wqkv8  fp8 [1536][512] (x16)         786,432
//   wproj8 fp8 [512][512] (x16, sigma)   262,144
//   stats  f32 [128][2]                    1,024
//   xnT8   fp8 [4][4096][512]          8,388,608
//   QKt8   fp8 [4][4096][1024](sig)   16,777,216
//   V8     fp8 [4][512][4096] (sig)    8,388,608
//   hmT8   fp8 [4][4096][512] (x16,sig) 8,388,608
extern "C" void kernel_launch(void* const* d_in, const int* in_sizes, int n_in,
                              void* d_out, int out_size, void* d_ws, size_t ws_size,
                              hipStream_t stream) {
  const float* x      = (const float*)d_in[0];
  const float* norm_w = (const float*)d_in[1];
  const float* norm_b = (const float*)d_in[2];
  const float* qkv_w  = (const float*)d_in[3];
  const float* qkv_b  = (const float*)d_in[4];
  const float* proj_w = (const float*)d_in[5];
  const float* proj_b = (const float*)d_in[6];
  float* out = (float*)d_out;

  char* ws = (char*)d_ws;
  size_t o = 0;
  fp8_t* wqkv8  = (fp8_t*)(ws + o); o += (size_t)1536 * 512;
  fp8_t* wproj8 = (fp8_t*)(ws + o); o += (size_t)512 * 512;
  float* stats  = (float*)(ws + o); o += 128 * 2 * 4;
  fp8_t* xnT8   = (fp8_t*)(ws + o); o += (size_t)B_ * HW_ * C_;
  fp8_t* QKt8   = (fp8_t*)(ws + o); o += (size_t)B_ * HW_ * 1024;
  fp8_t* V8     = (fp8_t*)(ws + o); o += (size_t)B_ * C_ * HW_;
  fp8_t* hmT8   = (fp8_t*)(ws + o); o += (size_t)B_ * HW_ * C_;

  cast_w_kernel<<<1024, 256, 0, stream>>>(qkv_w, proj_w, wqkv8, wproj8);
  hipMemsetAsync(stats, 0, 128 * 2 * sizeof(float), stream);
  gn_partial_kernel<<<1024, 256, 0, stream>>>(x, stats);
  norm_tr_kernel<<<dim3(HW_ / 64, C_ / 64, B_), 256, 0, stream>>>(x, stats, norm_w, norm_b, xnT8);
  qk_gemm_kernel<<<dim3(1024 / 128, HW_ / 128, B_), 256, 0, stream>>>(xnT8, wqkv8, qkv_b, QKt8);
  v_gemm_kernel<<<dim3(HW_ / 128, C_ / 128, B_), 256, 0, stream>>>(wqkv8, xnT8, qkv_b, V8);
  fused_attn_kernel<<<512, 512, 0, stream>>>(QKt8, V8, hmT8);
  proj_gemm_kernel<<<dim3(HW_ / 128, C_ / 128, B_), 256, 0, stream>>>(
      wproj8, hmT8, proj_b, x, out);
}

// Round 3
// 235.612 us; speedup vs baseline: 2.4998x; 2.4998x over previous
//
#include <hip/hip_runtime.h>
#include <hip/hip_fp8.h>
#include <cstdint>
#include <cmath>

// Problem constants
#define B_   4
#define C_   512
#define HW_  4096
#define G_   32
#define CPG_ 16
#define EPS_ 1e-6f
#define SCALE_ 0.04419417382415922f  // 1/sqrt(512)
#define PSCALE_ 0.0625f              // P pre-scale; cancels in acc/rowsum ratio

// ---------------------------------------------------------------------------
// Column permutation (sigma): GEMM epilogues store outputs in the MFMA
// C-layout packed order. Within each 64-col group, stored position
// p = fr*4 + j holds true column c = j*16 + fr. Invariant under contraction
// as long as producer & consumer agree.
//
// Weight scaling: fp8 weights are stored x16; the MFMA e8m0 scale operand
// 0x7B (= 2^-4) folds the 1/16 back in HW. Same trick for hmT8.
//
// R11: fusion arc abandoned (R9: 1 block/CU lockstep, 164us; R10: L2 thrash,
// FETCH 20->235MB, 452us). Reverted to the verified R0 7-kernel pipeline and
// fixed the shared GEMM mainloop instead: the old loop staged tile t and
// IMMEDIATELY drained it (__syncthreads => vmcnt(0)), exposing the full L2
// round trip every K-step (~240+ cyc vs 138 cyc of MFMA -> 24% MfmaUtil).
// New mainloop = T3 "minimum 2-phase" recipe: double-buffered LDS, stage
// tile t+1 BEFORE computing tile t, counted s_waitcnt vmcnt(8), raw
// s_barrier (never a full drain inside the loop), setprio(1) around MFMAs.
//   iter t: issue 8 cp16 -> buf[cur^1]   (flies across compute)
//           vmcnt(8)  = drain exactly the 8 older (tile t) cp16s
//           s_barrier = tile t visible to all waves
//           ds_read buf[cur] frags; MFMA cluster (setprio 1)
//           s_barrier = all reads of buf[cur] done (lgkm drained by MFMA
//                       operand waits) before next iter overwrites it
// ---------------------------------------------------------------------------

typedef __bf16 bf16_t;
typedef __bf16 bf16x8 __attribute__((ext_vector_type(8)));
typedef float  f32x4  __attribute__((ext_vector_type(4)));
typedef int    i32x4  __attribute__((ext_vector_type(4)));
typedef int    i32x8  __attribute__((ext_vector_type(8)));
typedef unsigned int u32;
typedef __hip_fp8_e4m3 fp8_t;  // OCP e4m3fn on gfx950

// Async global->LDS copy, 16B per lane. LDS dest is wave-uniform base + lane*16.
__device__ __forceinline__ void cp16(const void* g, void* l) {
  __builtin_amdgcn_global_load_lds((__attribute__((address_space(1))) u32*)(g),
                                   (__attribute__((address_space(3))) u32*)(l),
                                   16, 0, 0);
}

__device__ __forceinline__ void zero_acc(f32x4 acc[4][4]) {
  f32x4 z = {0.f, 0.f, 0.f, 0.f};
#pragma unroll
  for (int i = 0; i < 4; ++i)
#pragma unroll
    for (int j = 0; j < 4; ++j) acc[i][j] = z;
}

// MX-fp8 BT GEMM mainloop (BK=128): mfma_scale_f32_16x16x128_f8f6f4, fmt 0
// (e4m3), per-operand e8m0 scales SA/SB (0x7F = 1.0, 0x7B = 2^-4).
// LDS rows are 128 B (8 chunks); chunk-rotation swizzle mod 8 keeps staging
// and the paired ds_read_b128 fragment reads at the LDS bank floor.
// Double-buffered (2x32 KB) with counted vmcnt — see header comment.
template <bool ROWSUM, int SA = 0x7F, int SB = 0x7F>
__device__ __forceinline__ void gemm_bt_mx(const unsigned char* __restrict__ A,
                                           const unsigned char* __restrict__ B,
                                           int K, int lda, int ldb,
                                           f32x4 acc[4][4], f32x4 accl[4]) {
  __shared__ __align__(16) unsigned char As[2][128 * 128];
  __shared__ __align__(16) unsigned char Bs[2][128 * 128];
  const int tid  = threadIdx.x;
  const int wave = tid >> 6;
  const int lane = tid & 63;
  const int wm = (wave >> 1) * 64;
  const int wn = (wave & 1) * 64;
  // staging: per cp16 call lane covers row (lane>>3), LDS chunk (lane&7);
  // rotation: LDS chunk c of row r holds global chunk (c - r) & 7.
  const int srow = lane >> 3;
  const int gch  = ((lane & 7) - srow) & 7;
  const unsigned char* gA = A + (size_t)(wave * 32 + srow) * lda + gch * 16;
  const unsigned char* gB = B + (size_t)(wave * 32 + srow) * ldb + gch * 16;
  const int lofs = wave * 32 * 128;
  const int fr = lane & 15;
  const int q  = lane >> 4;
  // lane wants global chunks 2q, 2q+1 of its row (32 B = K-128 fragment)
  const int co0 = ((2 * q     + fr) & 7) * 16;
  const int co1 = ((2 * q + 1 + fr) & 7) * 16;
  const i32x8 vones = {0x38383838, 0x38383838, 0x38383838, 0x38383838,
                       0x38383838, 0x38383838, 0x38383838, 0x38383838};

  const int nT = K >> 7;
  // prologue: stage tile 0 into buffer 0
#pragma unroll
  for (int cc = 0; cc < 4; ++cc) {
    cp16(gA + (size_t)(cc * 8) * lda, &As[0][lofs + cc * 1024]);
    cp16(gB + (size_t)(cc * 8) * ldb, &Bs[0][lofs + cc * 1024]);
  }
  gA += 128; gB += 128;

#pragma unroll 1
  for (int t = 0; t < nT; ++t) {
    const int cur = t & 1;
    if (t + 1 < nT) {
      // stage tile t+1 into the other buffer; it flies across this tile's
      // compute and is drained by next iteration's vmcnt(8).
#pragma unroll
      for (int cc = 0; cc < 4; ++cc) {
        cp16(gA + (size_t)(cc * 8) * lda, &As[cur ^ 1][lofs + cc * 1024]);
        cp16(gB + (size_t)(cc * 8) * ldb, &Bs[cur ^ 1][lofs + cc * 1024]);
      }
      gA += 128; gB += 128;
      asm volatile("s_waitcnt vmcnt(8)" ::: "memory");  // tile t resident
    } else {
      asm volatile("s_waitcnt vmcnt(0)" ::: "memory");  // last tile resident
    }
    __builtin_amdgcn_s_barrier();   // tile t visible to all waves

    i32x8 a[4], b[4];
    const unsigned char* Ab = As[cur];
    const unsigned char* Bb = Bs[cur];
#pragma unroll
    for (int i = 0; i < 4; ++i) {
      const int ro = (wm + i * 16 + fr) * 128;
      i32x4 lo = *(const i32x4*)(Ab + ro + co0);
      i32x4 hi = *(const i32x4*)(Ab + ro + co1);
      a[i] = __builtin_shufflevector(lo, hi, 0, 1, 2, 3, 4, 5, 6, 7);
    }
#pragma unroll
    for (int j = 0; j < 4; ++j) {
      const int ro = (wn + j * 16 + fr) * 128;
      i32x4 lo = *(const i32x4*)(Bb + ro + co0);
      i32x4 hi = *(const i32x4*)(Bb + ro + co1);
      b[j] = __builtin_shufflevector(lo, hi, 0, 1, 2, 3, 4, 5, 6, 7);
    }
    __builtin_amdgcn_s_setprio(1);
#pragma unroll
    for (int i = 0; i < 4; ++i) {
#pragma unroll
      for (int j = 0; j < 4; ++j)
        acc[i][j] = __builtin_amdgcn_mfma_scale_f32_16x16x128_f8f6f4(
            a[i], b[j], acc[i][j], 0, 0, 0, SA, 0, SB);
      if (ROWSUM)
        accl[i] = __builtin_amdgcn_mfma_scale_f32_16x16x128_f8f6f4(
            a[i], vones, accl[i], 0, 0, 0, SA, 0, 0x7F);
    }
    __builtin_amdgcn_s_setprio(0);
    __builtin_amdgcn_s_barrier();   // all reads of buf[cur] done
  }
}

// ---------------- small prep kernels ----------------

// wqkv8 = fp8(qkv_w * 16), plain layout (k-dim = un-permuted input c).
// wproj8 = fp8(proj_w * 16) with sigma-permuted c columns to match hmT8.
__global__ void __launch_bounds__(256) cast_w_kernel(const float* __restrict__ qkv_w,
                                                     const float* __restrict__ proj_w,
                                                     fp8_t* __restrict__ wqkv8,
                                                     fp8_t* __restrict__ wproj8) {
  const int idx = blockIdx.x * 256 + threadIdx.x;   // quad index
  const int t = idx * 4;
  const int nq = 1536 * 512;
  if (t < nq) {
    u32 dw = 0;
    dw = (u32)__builtin_amdgcn_cvt_pk_fp8_f32(qkv_w[t] * 16.f, qkv_w[t + 1] * 16.f, (int)dw, false);
    dw = (u32)__builtin_amdgcn_cvt_pk_fp8_f32(qkv_w[t + 2] * 16.f, qkv_w[t + 3] * 16.f, (int)dw, true);
    *(u32*)((unsigned char*)wqkv8 + t) = dw;
  } else {
    const int tt = t - nq;          // o*512 + p, p multiple of 4
    const int o = tt >> 9;
    const int p = tt & 511;
    float v[4];
#pragma unroll
    for (int e = 0; e < 4; ++e) {
      const int pe = p + e;
      const int off = pe & 63;
      const int c = (pe & ~63) + ((off & 3) << 4) + (off >> 2);  // sigma(pe)
      v[e] = proj_w[(o << 9) + c] * 16.f;
    }
    u32 dw = 0;
    dw = (u32)__builtin_amdgcn_cvt_pk_fp8_f32(v[0], v[1], (int)dw, false);
    dw = (u32)__builtin_amdgcn_cvt_pk_fp8_f32(v[2], v[3], (int)dw, true);
    *(u32*)((unsigned char*)wproj8 + tt) = dw;
  }
}

// Partial GroupNorm stats: 8 hw-chunks per group -> 1024 blocks, 2 atomics each.
__global__ void __launch_bounds__(256) gn_partial_kernel(const float* __restrict__ x,
                                                         float* __restrict__ stats) {
  __shared__ float rs[256], rss[256];
  const int bg = blockIdx.x >> 3;       // group id 0..127
  const int ch = blockIdx.x & 7;        // hw chunk 0..7
  const float4* base = (const float4*)(x + (size_t)bg * (CPG_ * HW_)) +
                       (size_t)ch * (CPG_ * HW_ / 4 / 8);
  float s = 0.f, ss = 0.f;
  for (int i = threadIdx.x; i < CPG_ * HW_ / 4 / 8; i += 256) {
    float4 v = base[i];
    s  += v.x + v.y + v.z + v.w;
    ss += v.x * v.x + v.y * v.y + v.z * v.z + v.w * v.w;
  }
  rs[threadIdx.x] = s; rss[threadIdx.x] = ss;
  __syncthreads();
  for (int st = 128; st > 0; st >>= 1) {
    if ((int)threadIdx.x < st) {
      rs[threadIdx.x]  += rs[threadIdx.x + st];
      rss[threadIdx.x] += rss[threadIdx.x + st];
    }
    __syncthreads();
  }
  if (threadIdx.x == 0) {
    atomicAdd(&stats[bg * 2 + 0], rs[0]);
    atomicAdd(&stats[bg * 2 + 1], rss[0]);
  }
}

// normalize + transpose: x[b][c][i] (fp32) -> xnT8[b][i][c] (fp8, plain order)
__global__ void __launch_bounds__(256) norm_tr_kernel(const float* __restrict__ x,
                                                      const float* __restrict__ stats,
                                                      const float* __restrict__ nw,
                                                      const float* __restrict__ nb,
                                                      fp8_t* __restrict__ xnT8) {
  __shared__ float tile[64][65];   // [c_off][i_off]
  const int b  = blockIdx.z;
  const int i0 = blockIdx.x * 64;   // hw
  const int c0 = blockIdx.y * 64;   // channel
  const int tx = threadIdx.x & 63;
  const int ty = threadIdx.x >> 6;  // 0..3
  const int cbase = c0 + ty * 16;
  const int g = cbase >> 4;         // group const across r (16 channels per ty)
  const float inv = 1.f / (float)(CPG_ * HW_);
  const float sum  = stats[(b * G_ + g) * 2 + 0];
  const float ssum = stats[(b * G_ + g) * 2 + 1];
  const float mean = sum * inv;
  const float rstd = rsqrtf(ssum * inv - mean * mean + EPS_);
#pragma unroll
  for (int r = 0; r < 16; ++r) {
    const int c = cbase + r;
    float v = x[((size_t)b * C_ + c) * HW_ + i0 + tx];
    tile[ty * 16 + r][tx] = (v - mean) * rstd * nw[c] + nb[c];
  }
  __syncthreads();
  const int il = threadIdx.x >> 2;
  const int q4 = threadIdx.x & 3;
#pragma unroll
  for (int m = 0; m < 4; ++m) {
    const int cq = q4 + m * 4;     // 0..15
    u32 dw = 0;
    dw = (u32)__builtin_amdgcn_cvt_pk_fp8_f32(tile[cq * 4 + 0][il], tile[cq * 4 + 1][il], (int)dw, false);
    dw = (u32)__builtin_amdgcn_cvt_pk_fp8_f32(tile[cq * 4 + 2][il], tile[cq * 4 + 3][il], (int)dw, true);
    *(u32*)((unsigned char*)xnT8 + ((size_t)b * HW_ + i0 + il) * C_ + c0 + cq * 4) = dw;
  }
}

// ---------------- GEMM kernels ----------------

// QKt8[b][i][sigma-pos o] = fp8( xnT8 . wqkv8*2^-4 + bias ); MX GEMM, K=512.
__global__ void __launch_bounds__(256) qk_gemm_kernel(const fp8_t* __restrict__ xnT8,
                                                      const fp8_t* __restrict__ wqkv8,
                                                      const float* __restrict__ qkv_b,
                                                      fp8_t* __restrict__ QKt8) {
  const int b = blockIdx.z;
  f32x4 acc[4][4]; zero_acc(acc);
  const unsigned char* A  = (const unsigned char*)xnT8 + ((size_t)b * HW_ + blockIdx.y * 128) * C_;
  const unsigned char* Bp = (const unsigned char*)wqkv8 + (size_t)blockIdx.x * 128 * C_;
  gemm_bt_mx<false, 0x7F, 0x7B>(A, Bp, C_, C_, C_, acc, nullptr);
  const int lane = threadIdx.x & 63, wave = threadIdx.x >> 6;
  const int wm = (wave >> 1) * 64, wn = (wave & 1) * 64;
  const int fr = lane & 15, q = lane >> 4;
  const int r0 = blockIdx.y * 128 + wm + (q << 2);
  const int cb = blockIdx.x * 128 + wn;       // 64-col group base (true & stored)
  float bias[4];
#pragma unroll
  for (int j = 0; j < 4; ++j) bias[j] = qkv_b[cb + fr + j * 16];  // true cols
#pragma unroll
  for (int i = 0; i < 4; ++i)
#pragma unroll
    for (int r = 0; r < 4; ++r) {
      const int row = r0 + i * 16 + r;
      u32 dw = 0;
      dw = (u32)__builtin_amdgcn_cvt_pk_fp8_f32(acc[i][0][r] + bias[0],
                                                acc[i][1][r] + bias[1], (int)dw, false);
      dw = (u32)__builtin_amdgcn_cvt_pk_fp8_f32(acc[i][2][r] + bias[2],
                                                acc[i][3][r] + bias[3], (int)dw, true);
      *(u32*)((unsigned char*)QKt8 + ((size_t)b * HW_ + row) * 1024 + cb + fr * 4) = dw;
    }
}

// V8[b][c][sigma-pos j] = fp8( wqkv8_v*2^-4 . xnT8 + bias ); MX GEMM, K=512.
__global__ void __launch_bounds__(256) v_gemm_kernel(const fp8_t* __restrict__ wqkv8,
                                                     const fp8_t* __restrict__ xnT8,
                                                     const float* __restrict__ qkv_b,
                                                     fp8_t* __restrict__ V8) {
  const int b = blockIdx.z;
  f32x4 acc[4][4]; zero_acc(acc);
  const unsigned char* A  = (const unsigned char*)wqkv8 + (size_t)(1024 + blockIdx.y * 128) * C_;
  const unsigned char* Bp = (const unsigned char*)xnT8 + ((size_t)b * HW_ + blockIdx.x * 128) * C_;
  gemm_bt_mx<false, 0x7B, 0x7F>(A, Bp, C_, C_, C_, acc, nullptr);
  const int lane = threadIdx.x & 63, wave = threadIdx.x >> 6;
  const int wm = (wave >> 1) * 64, wn = (wave & 1) * 64;
  const int fr = lane & 15, q = lane >> 4;
  const int r0 = blockIdx.y * 128 + wm + (q << 2);
  const int cb = blockIdx.x * 128 + wn;       // hw 64-group base
#pragma unroll
  for (int i = 0; i < 4; ++i)
#pragma unroll
    for (int r = 0; r < 4; ++r) {
      const int row = r0 + i * 16 + r;        // c channel (row of V8)
      const float bias = qkv_b[1024 + row];
      u32 dw = 0;
      dw = (u32)__builtin_amdgcn_cvt_pk_fp8_f32(acc[i][0][r] + bias,
                                                acc[i][1][r] + bias, (int)dw, false);
      dw = (u32)__builtin_amdgcn_cvt_pk_fp8_f32(acc[i][2][r] + bias,
                                                acc[i][3][r] + bias, (int)dw, true);
      *(u32*)((unsigned char*)V8 + ((size_t)b * C_ + row) * HW_ + cb + fr * 4) = dw;
    }
}

// P8[b][i][sigma-pos j] = fp8( PSCALE * exp(scale * q_i.k_j) ); MX-fp8 GEMM.
// XCD-aware 1-D grid: the 32 K-panel blocks sharing a Q row-panel are
// dispatch-adjacent on one XCD (QKt8 panels stay L2-hot per XCD).
__global__ void __launch_bounds__(256) sexp_gemm_kernel(const fp8_t* __restrict__ QKt8,
                                                        fp8_t* __restrict__ P8) {
  const int n   = blockIdx.x;            // 4096 blocks
  const int xcd = n & 7;
  const int p   = n >> 3;                // 0..511 within XCD
  const int xb  = p & 31;                // K panel (fastest -> share Q panel)
  const int grp = xcd * 16 + (p >> 5);   // 0..127 = (yb, b) combo
  const int yb  = grp & 31;              // Q panel
  const int b   = grp >> 5;              // batch

  const unsigned char* QKtb = (const unsigned char*)QKt8 + (size_t)b * HW_ * 1024;
  fp8_t* Pb = P8 + (size_t)b * HW_ * HW_;
  f32x4 acc[4][4]; zero_acc(acc);
  const unsigned char* A  = QKtb + (size_t)yb * 128 * 1024;        // Q rows
  const unsigned char* Bp = QKtb + 512 + (size_t)xb * 128 * 1024;  // K rows
  gemm_bt_mx<false>(A, Bp, 512, 1024, 1024, acc, nullptr);
  const int lane = threadIdx.x & 63, wave = threadIdx.x >> 6;
  const int wm = (wave >> 1) * 64, wn = (wave & 1) * 64;
  const int fr = lane & 15, q = lane >> 4;
  const int r0 = yb * 128 + wm + (q << 2);
  const int cb = xb * 128 + wn;          // j 64-group base
#pragma unroll
  for (int i = 0; i < 4; ++i)
#pragma unroll
    for (int r = 0; r < 4; ++r) {
      const int row = r0 + i * 16 + r;
      float e0 = __expf(acc[i][0][r] * SCALE_) * PSCALE_;
      float e1 = __expf(acc[i][1][r] * SCALE_) * PSCALE_;
      float e2 = __expf(acc[i][2][r] * SCALE_) * PSCALE_;
      float e3 = __expf(acc[i][3][r] * SCALE_) * PSCALE_;
      u32 dw = 0;
      dw = (u32)__builtin_amdgcn_cvt_pk_fp8_f32(e0, e1, (int)dw, false);
      dw = (u32)__builtin_amdgcn_cvt_pk_fp8_f32(e2, e3, (int)dw, true);
      *(u32*)((unsigned char*)Pb + (size_t)row * HW_ + cb + fr * 4) = dw;
    }
}

// hmT8[b][i][sigma-pos c] = fp8( 16 * (sum_j P8 * V8) / rowsum(P8) )
// MX-fp8 GEMM with ones-MFMA row sums; XCD-aware block remap for P L2 reuse.
__global__ void __launch_bounds__(256) pv_gemm_kernel(const fp8_t* __restrict__ P8,
                                                      const fp8_t* __restrict__ V8,
                                                      fp8_t* __restrict__ hmT8) {
  // decode swizzled block id: n = 512 blocks total
  const int n   = blockIdx.x;
  const int xcd = n & 7;           // XCD (round-robin heuristic)
  const int p   = n >> 3;          // 0..63, position within XCD
  const int xb  = p & 3;           // C panel (fastest -> adjacent blocks share P)
  const int grp = xcd * 16 + (p >> 2);  // 0..127 = (y,z) group
  const int yb  = grp & 31;        // HW panel
  const int b   = grp >> 5;        // batch

  const unsigned char* A  = (const unsigned char*)P8 + (size_t)b * HW_ * HW_ +
                            (size_t)yb * 128 * HW_;
  const unsigned char* Bp = (const unsigned char*)V8 + (size_t)b * C_ * HW_ +
                            (size_t)xb * 128 * HW_;
  fp8_t* hmTb = hmT8 + (size_t)b * HW_ * C_;

  f32x4 acc[4][4]; zero_acc(acc);
  f32x4 accl[4];
  {
    f32x4 z = {0.f, 0.f, 0.f, 0.f};
#pragma unroll
    for (int i = 0; i < 4; ++i) accl[i] = z;
  }
  gemm_bt_mx<true>(A, Bp, HW_, HW_, HW_, acc, accl);

  const int lane = threadIdx.x & 63, wave = threadIdx.x >> 6;
  const int wm = (wave >> 1) * 64, wn = (wave & 1) * 64;
  const int fr = lane & 15, q = lane >> 4;
  const int r0 = yb * 128 + wm + (q << 2);
  const int cb = xb * 128 + wn;   // c 64-group base (stored sigma-packed)
#pragma unroll
  for (int i = 0; i < 4; ++i)
#pragma unroll
    for (int r = 0; r < 4; ++r) {
      const int row = r0 + i * 16 + r;
      const float rl = 16.f / accl[i][r];   // x16 for fp8 range; undone by 2^-4 in proj
      u32 dw = 0;
      dw = (u32)__builtin_amdgcn_cvt_pk_fp8_f32(acc[i][0][r] * rl, acc[i][1][r] * rl, (int)dw, false);
      dw = (u32)__builtin_amdgcn_cvt_pk_fp8_f32(acc[i][2][r] * rl, acc[i][3][r] * rl, (int)dw, true);
      *(u32*)((unsigned char*)hmTb + (size_t)row * C_ + cb + fr * 4) = dw;
    }
}

// out[b][o][i] = x[b][o][i] + proj_b[o] + (wproj8*2^-4)(sigma) . (hmT8*2^-4)(sigma)
__global__ void __launch_bounds__(256) proj_gemm_kernel(const fp8_t* __restrict__ wproj8,
                                                        const fp8_t* __restrict__ hmT8,
                                                        const float* __restrict__ proj_b,
                                                        const float* __restrict__ x,
                                                        float* __restrict__ out) {
  const int b = blockIdx.z;
  f32x4 acc[4][4]; zero_acc(acc);
  const unsigned char* A  = (const unsigned char*)wproj8 + (size_t)blockIdx.y * 128 * C_;
  const unsigned char* Bp = (const unsigned char*)hmT8 + ((size_t)b * HW_ + blockIdx.x * 128) * C_;
  gemm_bt_mx<false, 0x7B, 0x7B>(A, Bp, C_, C_, C_, acc, nullptr);
  const int lane = threadIdx.x & 63, wave = threadIdx.x >> 6;
  const int wm = (wave >> 1) * 64, wn = (wave & 1) * 64;
  const int r0 = blockIdx.y * 128 + wm + ((lane >> 4) << 2);
  const int c0 = blockIdx.x * 128 + wn + (lane & 15);
#pragma unroll
  for (int i = 0; i < 4; ++i)
#pragma unroll
    for (int r = 0; r < 4; ++r) {
      const int row = r0 + i * 16 + r;
      const float bias = proj_b[row];
#pragma unroll
      for (int j = 0; j < 4; ++j) {
        const int col = c0 + j * 16;
        const size_t idx = ((size_t)b * C_ + row) * HW_ + col;
        out[idx] = x[idx] + bias + acc[i][j][r];
      }
    }
}

// ---------------- launch ----------------
// Workspace layout (bytes), total ~110 MB:
//   wqkv8  fp8 [1536][512] (x16)         786,432
//   wproj8 fp8 [512][512] (x16, sigma)   262,144
//   stats  f32 [128][2]                    1,024
//   xnT8   fp8 [4][4096][512]          8,388,608
//   QKt8   fp8 [4][4096][1024](sig)   16,777,216
//   V8     fp8 [4][512][4096] (sig)    8,388,608
//   hmT8   fp8 [4][4096][512] (x16,sig) 8,388,608
//   P8     fp8 [4][4096][4096](sig)   67,108,864
extern "C" void kernel_launch(void* const* d_in, const int* in_sizes, int n_in,
                              void* d_out, int out_size, void* d_ws, size_t ws_size,
                              hipStream_t stream) {
  const float* x      = (const float*)d_in[0];
  const float* norm_w = (const float*)d_in[1];
  const float* norm_b = (const float*)d_in[2];
  const float* qkv_w  = (const float*)d_in[3];
  const float* qkv_b  = (const float*)d_in[4];
  const float* proj_w = (const float*)d_in[5];
  const float* proj_b = (const float*)d_in[6];
  float* out = (float*)d_out;

  char* ws = (char*)d_ws;
  size_t o = 0;
  fp8_t* wqkv8  = (fp8_t*)(ws + o); o += (size_t)1536 * 512;
  fp8_t* wproj8 = (fp8_t*)(ws + o); o += (size_t)512 * 512;
  float* stats  = (float*)(ws + o); o += 128 * 2 * 4;
  fp8_t* xnT8   = (fp8_t*)(ws + o); o += (size_t)B_ * HW_ * C_;
  fp8_t* QKt8   = (fp8_t*)(ws + o); o += (size_t)B_ * HW_ * 1024;
  fp8_t* V8     = (fp8_t*)(ws + o); o += (size_t)B_ * C_ * HW_;
  fp8_t* hmT8   = (fp8_t*)(ws + o); o += (size_t)B_ * HW_ * C_;
  fp8_t* P8     = (fp8_t*)(ws + o); o += (size_t)B_ * HW_ * HW_;

  cast_w_kernel<<<1024, 256, 0, stream>>>(qkv_w, proj_w, wqkv8, wproj8);
  hipMemsetAsync(stats, 0, 128 * 2 * sizeof(float), stream);
  gn_partial_kernel<<<1024, 256, 0, stream>>>(x, stats);
  norm_tr_kernel<<<dim3(HW_ / 64, C_ / 64, B_), 256, 0, stream>>>(x, stats, norm_w, norm_b, xnT8);
  qk_gemm_kernel<<<dim3(1024 / 128, HW_ / 128, B_), 256, 0, stream>>>(xnT8, wqkv8, qkv_b, QKt8);
  v_gemm_kernel<<<dim3(HW_ / 128, C_ / 128, B_), 256, 0, stream>>>(wqkv8, xnT8, qkv_b, V8);
  sexp_gemm_kernel<<<4096, 256, 0, stream>>>(QKt8, P8);
  pv_gemm_kernel<<<512, 256, 0, stream>>>(P8, V8, hmT8);
  proj_gemm_kernel<<<dim3(HW_ / 128, C_ / 128, B_), 256, 0, stream>>>(
      wproj8, hmT8, proj_b, x, out);
}

// Round 4
// 229.726 us; speedup vs baseline: 2.5638x; 1.0256x over previous
//
#include <hip/hip_runtime.h>
#include <hip/hip_fp8.h>
#include <cstdint>
#include <cmath>

// Problem constants
#define B_   4
#define C_   512
#define HW_  4096
#define G_   32
#define CPG_ 16
#define EPS_ 1e-6f
#define SCALE_ 0.04419417382415922f  // 1/sqrt(512)
#define PSCALE_ 0.0625f              // P pre-scale; cancels in acc/rowsum ratio
#define SEXPC_ 0.063758715306f       // SCALE * log2(e): exp(a*S)*2^-4 = 2^(a*SEXPC - 4)

// ---------------------------------------------------------------------------
// Column permutation (sigma): GEMM epilogues store outputs in the MFMA
// C-layout packed order. Within each 64-col group, stored position
// p = fr*4 + j holds true column c = j*16 + fr. Invariant under contraction
// as long as producer & consumer agree.
//
// Weight scaling: fp8 weights are stored x16; the MFMA e8m0 scale operand
// 0x7B (= 2^-4) folds the 1/16 back in HW. Same trick for hmT8.
//
// R12 (post-mortem R11): dbuf+counted-vmcnt was NEUTRAL (55.4us, MfmaUtil
// 23.6) — replicates m99/m131: with >=2 blocks/CU, inter-block overlap
// already hides staging; and R0(3blk) == R3(2blk) rules out occupancy.
// Critical path is intra-wave serial VALU: VALUBusy(38%) > MfmaUtil(24%).
// So: (1) sexp epilogue exp2-fold (fma+v_exp replaces mul,mul,exp,mul);
// (2) pv epilogue v_rcp instead of full div; (3) merge qk+v and gn+cast
// dispatches (LDS passed by pointer so merged kernels share one buffer).
// ---------------------------------------------------------------------------

typedef __bf16 bf16_t;
typedef __bf16 bf16x8 __attribute__((ext_vector_type(8)));
typedef float  f32x4  __attribute__((ext_vector_type(4)));
typedef int    i32x4  __attribute__((ext_vector_type(4)));
typedef int    i32x8  __attribute__((ext_vector_type(8)));
typedef unsigned int u32;
typedef __hip_fp8_e4m3 fp8_t;  // OCP e4m3fn on gfx950

// Async global->LDS copy, 16B per lane. LDS dest is wave-uniform base + lane*16.
__device__ __forceinline__ void cp16(const void* g, void* l) {
  __builtin_amdgcn_global_load_lds((__attribute__((address_space(1))) u32*)(g),
                                   (__attribute__((address_space(3))) u32*)(l),
                                   16, 0, 0);
}

// Raw v_exp_f32 (2^x). s_nop 1 covers the trans->consumer wait-state
// conservatively (inline asm is opaque to the hazard recognizer).
__device__ __forceinline__ float fexp2(float x) {
  float r;
  asm("v_exp_f32 %0, %1\n\ts_nop 1" : "=v"(r) : "v"(x));
  return r;
}

__device__ __forceinline__ void zero_acc(f32x4 acc[4][4]) {
  f32x4 z = {0.f, 0.f, 0.f, 0.f};
#pragma unroll
  for (int i = 0; i < 4; ++i)
#pragma unroll
    for (int j = 0; j < 4; ++j) acc[i][j] = z;
}

// MX-fp8 BT GEMM mainloop (BK=128): mfma_scale_f32_16x16x128_f8f6f4, fmt 0
// (e4m3), per-operand e8m0 scales SA/SB (0x7F = 1.0, 0x7B = 2^-4).
// LDS rows are 128 B (8 chunks); chunk-rotation swizzle mod 8 keeps staging
// and the paired ds_read_b128 fragment reads at the LDS bank floor.
// Double-buffered (2x16 KB per operand, caller-provided LDS), counted vmcnt.
template <bool ROWSUM, int SA = 0x7F, int SB = 0x7F>
__device__ __forceinline__ void gemm_bt_mx(const unsigned char* __restrict__ A,
                                           const unsigned char* __restrict__ B,
                                           int K, int lda, int ldb,
                                           f32x4 acc[4][4], f32x4 accl[4],
                                           unsigned char* AsB, unsigned char* BsB) {
  const int tid  = threadIdx.x;
  const int wave = tid >> 6;
  const int lane = tid & 63;
  const int wm = (wave >> 1) * 64;
  const int wn = (wave & 1) * 64;
  // staging: per cp16 call lane covers row (lane>>3), LDS chunk (lane&7);
  // rotation: LDS chunk c of row r holds global chunk (c - r) & 7.
  const int srow = lane >> 3;
  const int gch  = ((lane & 7) - srow) & 7;
  const unsigned char* gA = A + (size_t)(wave * 32 + srow) * lda + gch * 16;
  const unsigned char* gB = B + (size_t)(wave * 32 + srow) * ldb + gch * 16;
  const int lofs = wave * 32 * 128;
  const int fr = lane & 15;
  const int q  = lane >> 4;
  // lane wants global chunks 2q, 2q+1 of its row (32 B = K-128 fragment)
  const int co0 = ((2 * q     + fr) & 7) * 16;
  const int co1 = ((2 * q + 1 + fr) & 7) * 16;
  const i32x8 vones = {0x38383838, 0x38383838, 0x38383838, 0x38383838,
                       0x38383838, 0x38383838, 0x38383838, 0x38383838};

  const int nT = K >> 7;
  // prologue: stage tile 0 into buffer 0
#pragma unroll
  for (int cc = 0; cc < 4; ++cc) {
    cp16(gA + (size_t)(cc * 8) * lda, AsB + lofs + cc * 1024);
    cp16(gB + (size_t)(cc * 8) * ldb, BsB + lofs + cc * 1024);
  }
  gA += 128; gB += 128;

#pragma unroll 1
  for (int t = 0; t < nT; ++t) {
    const int cur = t & 1;
    if (t + 1 < nT) {
      // stage tile t+1 into the other buffer; it flies across this tile's
      // compute and is drained by next iteration's vmcnt(8).
#pragma unroll
      for (int cc = 0; cc < 4; ++cc) {
        cp16(gA + (size_t)(cc * 8) * lda, AsB + (cur ^ 1) * 16384 + lofs + cc * 1024);
        cp16(gB + (size_t)(cc * 8) * ldb, BsB + (cur ^ 1) * 16384 + lofs + cc * 1024);
      }
      gA += 128; gB += 128;
      asm volatile("s_waitcnt vmcnt(8)" ::: "memory");  // tile t resident
    } else {
      asm volatile("s_waitcnt vmcnt(0)" ::: "memory");  // last tile resident
    }
    __builtin_amdgcn_s_barrier();   // tile t visible to all waves

    i32x8 a[4], b[4];
    const unsigned char* Ab = AsB + cur * 16384;
    const unsigned char* Bb = BsB + cur * 16384;
#pragma unroll
    for (int i = 0; i < 4; ++i) {
      const int ro = (wm + i * 16 + fr) * 128;
      i32x4 lo = *(const i32x4*)(Ab + ro + co0);
      i32x4 hi = *(const i32x4*)(Ab + ro + co1);
      a[i] = __builtin_shufflevector(lo, hi, 0, 1, 2, 3, 4, 5, 6, 7);
    }
#pragma unroll
    for (int j = 0; j < 4; ++j) {
      const int ro = (wn + j * 16 + fr) * 128;
      i32x4 lo = *(const i32x4*)(Bb + ro + co0);
      i32x4 hi = *(const i32x4*)(Bb + ro + co1);
      b[j] = __builtin_shufflevector(lo, hi, 0, 1, 2, 3, 4, 5, 6, 7);
    }
    __builtin_amdgcn_s_setprio(1);
#pragma unroll
    for (int i = 0; i < 4; ++i) {
#pragma unroll
      for (int j = 0; j < 4; ++j)
        acc[i][j] = __builtin_amdgcn_mfma_scale_f32_16x16x128_f8f6f4(
            a[i], b[j], acc[i][j], 0, 0, 0, SA, 0, SB);
      if (ROWSUM)
        accl[i] = __builtin_amdgcn_mfma_scale_f32_16x16x128_f8f6f4(
            a[i], vones, accl[i], 0, 0, 0, SA, 0, 0x7F);
    }
    __builtin_amdgcn_s_setprio(0);
    __builtin_amdgcn_s_barrier();   // all reads of buf[cur] done
  }
}

// ---------------- prep: GroupNorm partials + weight casts (merged) ----------

// blocks [0,1024): partial GN stats (8 hw-chunks per group, 2 atomics each).
// blocks [1024,2048): wqkv8 = fp8(qkv_w*16) plain; wproj8 = fp8(proj_w*16)
// with sigma-permuted c columns.
__global__ void __launch_bounds__(256) prep_kernel(const float* __restrict__ x,
                                                   float* __restrict__ stats,
                                                   const float* __restrict__ qkv_w,
                                                   const float* __restrict__ proj_w,
                                                   fp8_t* __restrict__ wqkv8,
                                                   fp8_t* __restrict__ wproj8) {
  __shared__ float rs[256], rss[256];
  const int n = blockIdx.x;
  if (n < 1024) {
    const int bg = n >> 3;       // group id 0..127
    const int ch = n & 7;        // hw chunk 0..7
    const float4* base = (const float4*)(x + (size_t)bg * (CPG_ * HW_)) +
                         (size_t)ch * (CPG_ * HW_ / 4 / 8);
    float s = 0.f, ss = 0.f;
    for (int i = threadIdx.x; i < CPG_ * HW_ / 4 / 8; i += 256) {
      float4 v = base[i];
      s  += v.x + v.y + v.z + v.w;
      ss += v.x * v.x + v.y * v.y + v.z * v.z + v.w * v.w;
    }
    rs[threadIdx.x] = s; rss[threadIdx.x] = ss;
    __syncthreads();
    for (int st = 128; st > 0; st >>= 1) {
      if ((int)threadIdx.x < st) {
        rs[threadIdx.x]  += rs[threadIdx.x + st];
        rss[threadIdx.x] += rss[threadIdx.x + st];
      }
      __syncthreads();
    }
    if (threadIdx.x == 0) {
      atomicAdd(&stats[bg * 2 + 0], rs[0]);
      atomicAdd(&stats[bg * 2 + 1], rss[0]);
    }
  } else {
    const int idx = (n - 1024) * 256 + threadIdx.x;   // quad index
    const int t = idx * 4;
    const int nq = 1536 * 512;
    if (t < nq) {
      u32 dw = 0;
      dw = (u32)__builtin_amdgcn_cvt_pk_fp8_f32(qkv_w[t] * 16.f, qkv_w[t + 1] * 16.f, (int)dw, false);
      dw = (u32)__builtin_amdgcn_cvt_pk_fp8_f32(qkv_w[t + 2] * 16.f, qkv_w[t + 3] * 16.f, (int)dw, true);
      *(u32*)((unsigned char*)wqkv8 + t) = dw;
    } else {
      const int tt = t - nq;          // o*512 + p, p multiple of 4
      const int o = tt >> 9;
      const int p = tt & 511;
      float v[4];
#pragma unroll
      for (int e = 0; e < 4; ++e) {
        const int pe = p + e;
        const int off = pe & 63;
        const int c = (pe & ~63) + ((off & 3) << 4) + (off >> 2);  // sigma(pe)
        v[e] = proj_w[(o << 9) + c] * 16.f;
      }
      u32 dw = 0;
      dw = (u32)__builtin_amdgcn_cvt_pk_fp8_f32(v[0], v[1], (int)dw, false);
      dw = (u32)__builtin_amdgcn_cvt_pk_fp8_f32(v[2], v[3], (int)dw, true);
      *(u32*)((unsigned char*)wproj8 + tt) = dw;
    }
  }
}

// normalize + transpose: x[b][c][i] (fp32) -> xnT8[b][i][c] (fp8, plain order)
__global__ void __launch_bounds__(256) norm_tr_kernel(const float* __restrict__ x,
                                                      const float* __restrict__ stats,
                                                      const float* __restrict__ nw,
                                                      const float* __restrict__ nb,
                                                      fp8_t* __restrict__ xnT8) {
  __shared__ float tile[64][65];   // [c_off][i_off]
  const int b  = blockIdx.z;
  const int i0 = blockIdx.x * 64;   // hw
  const int c0 = blockIdx.y * 64;   // channel
  const int tx = threadIdx.x & 63;
  const int ty = threadIdx.x >> 6;  // 0..3
  const int cbase = c0 + ty * 16;
  const int g = cbase >> 4;         // group const across r (16 channels per ty)
  const float inv = 1.f / (float)(CPG_ * HW_);
  const float sum  = stats[(b * G_ + g) * 2 + 0];
  const float ssum = stats[(b * G_ + g) * 2 + 1];
  const float mean = sum * inv;
  const float rstd = rsqrtf(ssum * inv - mean * mean + EPS_);
#pragma unroll
  for (int r = 0; r < 16; ++r) {
    const int c = cbase + r;
    float v = x[((size_t)b * C_ + c) * HW_ + i0 + tx];
    tile[ty * 16 + r][tx] = (v - mean) * rstd * nw[c] + nb[c];
  }
  __syncthreads();
  const int il = threadIdx.x >> 2;
  const int q4 = threadIdx.x & 3;
#pragma unroll
  for (int m = 0; m < 4; ++m) {
    const int cq = q4 + m * 4;     // 0..15
    u32 dw = 0;
    dw = (u32)__builtin_amdgcn_cvt_pk_fp8_f32(tile[cq * 4 + 0][il], tile[cq * 4 + 1][il], (int)dw, false);
    dw = (u32)__builtin_amdgcn_cvt_pk_fp8_f32(tile[cq * 4 + 2][il], tile[cq * 4 + 3][il], (int)dw, true);
    *(u32*)((unsigned char*)xnT8 + ((size_t)b * HW_ + i0 + il) * C_ + c0 + cq * 4) = dw;
  }
}

// ---------------- GEMM kernels ----------------

// Merged qk+v projections (saves a dispatch; v's small grid rides qk's tail).
// blocks [0,1024): QKt8[b][i][sig o] = fp8( xnT8 . wqkv8*2^-4 + bias )
// blocks [1024,1536): V8[b][c][sig j] = fp8( wqkv8_v*2^-4 . xnT8 + bias )
__global__ void __launch_bounds__(256) qkv_gemm_kernel(const fp8_t* __restrict__ xnT8,
                                                       const fp8_t* __restrict__ wqkv8,
                                                       const float* __restrict__ qkv_b,
                                                       fp8_t* __restrict__ QKt8,
                                                       fp8_t* __restrict__ V8) {
  __shared__ __align__(16) unsigned char As[2 * 16384];
  __shared__ __align__(16) unsigned char Bs[2 * 16384];
  const int n = blockIdx.x;
  const int lane = threadIdx.x & 63, wave = threadIdx.x >> 6;
  const int wm = (wave >> 1) * 64, wn = (wave & 1) * 64;
  const int fr = lane & 15, q = lane >> 4;
  f32x4 acc[4][4]; zero_acc(acc);

  if (n < 1024) {
    const int xb = n & 7, yb = (n >> 3) & 31, b = n >> 8;
    const unsigned char* A  = (const unsigned char*)xnT8 + ((size_t)b * HW_ + yb * 128) * C_;
    const unsigned char* Bp = (const unsigned char*)wqkv8 + (size_t)xb * 128 * C_;
    gemm_bt_mx<false, 0x7F, 0x7B>(A, Bp, C_, C_, C_, acc, nullptr, As, Bs);
    const int r0 = yb * 128 + wm + (q << 2);
    const int cb = xb * 128 + wn;       // 64-col group base (true & stored)
    float bias[4];
#pragma unroll
    for (int j = 0; j < 4; ++j) bias[j] = qkv_b[cb + fr + j * 16];  // true cols
#pragma unroll
    for (int i = 0; i < 4; ++i)
#pragma unroll
      for (int r = 0; r < 4; ++r) {
        const int row = r0 + i * 16 + r;
        u32 dw = 0;
        dw = (u32)__builtin_amdgcn_cvt_pk_fp8_f32(acc[i][0][r] + bias[0],
                                                  acc[i][1][r] + bias[1], (int)dw, false);
        dw = (u32)__builtin_amdgcn_cvt_pk_fp8_f32(acc[i][2][r] + bias[2],
                                                  acc[i][3][r] + bias[3], (int)dw, true);
        *(u32*)((unsigned char*)QKt8 + ((size_t)b * HW_ + row) * 1024 + cb + fr * 4) = dw;
      }
  } else {
    const int m = n - 1024;
    const int xb = m & 31, yb = (m >> 5) & 3, b = m >> 7;
    const unsigned char* A  = (const unsigned char*)wqkv8 + (size_t)(1024 + yb * 128) * C_;
    const unsigned char* Bp = (const unsigned char*)xnT8 + ((size_t)b * HW_ + xb * 128) * C_;
    gemm_bt_mx<false, 0x7B, 0x7F>(A, Bp, C_, C_, C_, acc, nullptr, As, Bs);
    const int r0 = yb * 128 + wm + (q << 2);
    const int cb = xb * 128 + wn;       // hw 64-group base
#pragma unroll
    for (int i = 0; i < 4; ++i)
#pragma unroll
      for (int r = 0; r < 4; ++r) {
        const int row = r0 + i * 16 + r;        // c channel (row of V8)
        const float bias = qkv_b[1024 + row];
        u32 dw = 0;
        dw = (u32)__builtin_amdgcn_cvt_pk_fp8_f32(acc[i][0][r] + bias,
                                                  acc[i][1][r] + bias, (int)dw, false);
        dw = (u32)__builtin_amdgcn_cvt_pk_fp8_f32(acc[i][2][r] + bias,
                                                  acc[i][3][r] + bias, (int)dw, true);
        *(u32*)((unsigned char*)V8 + ((size_t)b * C_ + row) * HW_ + cb + fr * 4) = dw;
      }
  }
}

// P8[b][i][sigma-pos j] = fp8( 2^(scale*log2e * q_i.k_j - 4) ); MX-fp8 GEMM.
// XCD-aware 1-D grid: the 32 K-panel blocks sharing a Q row-panel are
// dispatch-adjacent on one XCD (QKt8 panels stay L2-hot per XCD).
__global__ void __launch_bounds__(256) sexp_gemm_kernel(const fp8_t* __restrict__ QKt8,
                                                        fp8_t* __restrict__ P8) {
  __shared__ __align__(16) unsigned char As[2 * 16384];
  __shared__ __align__(16) unsigned char Bs[2 * 16384];
  const int n   = blockIdx.x;            // 4096 blocks
  const int xcd = n & 7;
  const int p   = n >> 3;                // 0..511 within XCD
  const int xb  = p & 31;                // K panel (fastest -> share Q panel)
  const int grp = xcd * 16 + (p >> 5);   // 0..127 = (yb, b) combo
  const int yb  = grp & 31;              // Q panel
  const int b   = grp >> 5;              // batch

  const unsigned char* QKtb = (const unsigned char*)QKt8 + (size_t)b * HW_ * 1024;
  fp8_t* Pb = P8 + (size_t)b * HW_ * HW_;
  f32x4 acc[4][4]; zero_acc(acc);
  const unsigned char* A  = QKtb + (size_t)yb * 128 * 1024;        // Q rows
  const unsigned char* Bp = QKtb + 512 + (size_t)xb * 128 * 1024;  // K rows
  gemm_bt_mx<false>(A, Bp, 512, 1024, 1024, acc, nullptr, As, Bs);
  const int lane = threadIdx.x & 63, wave = threadIdx.x >> 6;
  const int wm = (wave >> 1) * 64, wn = (wave & 1) * 64;
  const int fr = lane & 15, q = lane >> 4;
  const int r0 = yb * 128 + wm + (q << 2);
  const int cb = xb * 128 + wn;          // j 64-group base
#pragma unroll
  for (int i = 0; i < 4; ++i)
#pragma unroll
    for (int r = 0; r < 4; ++r) {
      const int row = r0 + i * 16 + r;
      float e0 = fexp2(fmaf(acc[i][0][r], SEXPC_, -4.0f));
      float e1 = fexp2(fmaf(acc[i][1][r], SEXPC_, -4.0f));
      float e2 = fexp2(fmaf(acc[i][2][r], SEXPC_, -4.0f));
      float e3 = fexp2(fmaf(acc[i][3][r], SEXPC_, -4.0f));
      u32 dw = 0;
      dw = (u32)__builtin_amdgcn_cvt_pk_fp8_f32(e0, e1, (int)dw, false);
      dw = (u32)__builtin_amdgcn_cvt_pk_fp8_f32(e2, e3, (int)dw, true);
      *(u32*)((unsigned char*)Pb + (size_t)row * HW_ + cb + fr * 4) = dw;
    }
}

// hmT8[b][i][sigma-pos c] = fp8( 16 * (sum_j P8 * V8) / rowsum(P8) )
// MX-fp8 GEMM with ones-MFMA row sums; XCD-aware block remap for P L2 reuse.
__global__ void __launch_bounds__(256) pv_gemm_kernel(const fp8_t* __restrict__ P8,
                                                      const fp8_t* __restrict__ V8,
                                                      fp8_t* __restrict__ hmT8) {
  __shared__ __align__(16) unsigned char As[2 * 16384];
  __shared__ __align__(16) unsigned char Bs[2 * 16384];
  // decode swizzled block id: n = 512 blocks total
  const int n   = blockIdx.x;
  const int xcd = n & 7;           // XCD (round-robin heuristic)
  const int p   = n >> 3;          // 0..63, position within XCD
  const int xb  = p & 3;           // C panel (fastest -> adjacent blocks share P)
  const int grp = xcd * 16 + (p >> 2);  // 0..127 = (y,z) group
  const int yb  = grp & 31;        // HW panel
  const int b   = grp >> 5;        // batch

  const unsigned char* A  = (const unsigned char*)P8 + (size_t)b * HW_ * HW_ +
                            (size_t)yb * 128 * HW_;
  const unsigned char* Bp = (const unsigned char*)V8 + (size_t)b * C_ * HW_ +
                            (size_t)xb * 128 * HW_;
  fp8_t* hmTb = hmT8 + (size_t)b * HW_ * C_;

  f32x4 acc[4][4]; zero_acc(acc);
  f32x4 accl[4];
  {
    f32x4 z = {0.f, 0.f, 0.f, 0.f};
#pragma unroll
    for (int i = 0; i < 4; ++i) accl[i] = z;
  }
  gemm_bt_mx<true>(A, Bp, HW_, HW_, HW_, acc, accl, As, Bs);

  const int lane = threadIdx.x & 63, wave = threadIdx.x >> 6;
  const int wm = (wave >> 1) * 64, wn = (wave & 1) * 64;
  const int fr = lane & 15, q = lane >> 4;
  const int r0 = yb * 128 + wm + (q << 2);
  const int cb = xb * 128 + wn;   // c 64-group base (stored sigma-packed)
#pragma unroll
  for (int i = 0; i < 4; ++i)
#pragma unroll
    for (int r = 0; r < 4; ++r) {
      const int row = r0 + i * 16 + r;
      // x16 for fp8 range; undone by 2^-4 in proj. rcp: 1-ulp, fp8-invisible.
      const float rl = 16.f * __builtin_amdgcn_rcpf(accl[i][r]);
      u32 dw = 0;
      dw = (u32)__builtin_amdgcn_cvt_pk_fp8_f32(acc[i][0][r] * rl, acc[i][1][r] * rl, (int)dw, false);
      dw = (u32)__builtin_amdgcn_cvt_pk_fp8_f32(acc[i][2][r] * rl, acc[i][3][r] * rl, (int)dw, true);
      *(u32*)((unsigned char*)hmTb + (size_t)row * C_ + cb + fr * 4) = dw;
    }
}

// out[b][o][i] = x[b][o][i] + proj_b[o] + (wproj8*2^-4)(sigma) . (hmT8*2^-4)(sigma)
__global__ void __launch_bounds__(256) proj_gemm_kernel(const fp8_t* __restrict__ wproj8,
                                                        const fp8_t* __restrict__ hmT8,
                                                        const float* __restrict__ proj_b,
                                                        const float* __restrict__ x,
                                                        float* __restrict__ out) {
  __shared__ __align__(16) unsigned char As[2 * 16384];
  __shared__ __align__(16) unsigned char Bs[2 * 16384];
  const int b = blockIdx.z;
  f32x4 acc[4][4]; zero_acc(acc);
  const unsigned char* A  = (const unsigned char*)wproj8 + (size_t)blockIdx.y * 128 * C_;
  const unsigned char* Bp = (const unsigned char*)hmT8 + ((size_t)b * HW_ + blockIdx.x * 128) * C_;
  gemm_bt_mx<false, 0x7B, 0x7B>(A, Bp, C_, C_, C_, acc, nullptr, As, Bs);
  const int lane = threadIdx.x & 63, wave = threadIdx.x >> 6;
  const int wm = (wave >> 1) * 64, wn = (wave & 1) * 64;
  const int r0 = blockIdx.y * 128 + wm + ((lane >> 4) << 2);
  const int c0 = blockIdx.x * 128 + wn + (lane & 15);
#pragma unroll
  for (int i = 0; i < 4; ++i)
#pragma unroll
    for (int r = 0; r < 4; ++r) {
      const int row = r0 + i * 16 + r;
      const float bias = proj_b[row];
#pragma unroll
      for (int j = 0; j < 4; ++j) {
        const int col = c0 + j * 16;
        const size_t idx = ((size_t)b * C_ + row) * HW_ + col;
        out[idx] = x[idx] + bias + acc[i][j][r];
      }
    }
}

// ---------------- launch ----------------
// Workspace layout (bytes), total ~110 MB:
//   wqkv8  fp8 [1536][512] (x16)         786,432
//   wproj8 fp8 [512][512] (x16, sigma)   262,144
//   stats  f32 [128][2]                    1,024
//   xnT8   fp8 [4][4096][512]          8,388,608
//   QKt8   fp8 [4][4096][1024](sig)   16,777,216
//   V8     fp8 [4][512][4096] (sig)    8,388,608
//   hmT8   fp8 [4][4096][512] (x16,sig) 8,388,608
//   P8     fp8 [4][4096][4096](sig)   67,108,864
extern "C" void kernel_launch(void* const* d_in, const int* in_sizes, int n_in,
                              void* d_out, int out_size, void* d_ws, size_t ws_size,
                              hipStream_t stream) {
  const float* x      = (const float*)d_in[0];
  const float* norm_w = (const float*)d_in[1];
  const float* norm_b = (const float*)d_in[2];
  const float* qkv_w  = (const float*)d_in[3];
  const float* qkv_b  = (const float*)d_in[4];
  const float* proj_w = (const float*)d_in[5];
  const float* proj_b = (const float*)d_in[6];
  float* out = (float*)d_out;

  char* ws = (char*)d_ws;
  size_t o = 0;
  fp8_t* wqkv8  = (fp8_t*)(ws + o); o += (size_t)1536 * 512;
  fp8_t* wproj8 = (fp8_t*)(ws + o); o += (size_t)512 * 512;
  float* stats  = (float*)(ws + o); o += 128 * 2 * 4;
  fp8_t* xnT8   = (fp8_t*)(ws + o); o += (size_t)B_ * HW_ * C_;
  fp8_t* QKt8   = (fp8_t*)(ws + o); o += (size_t)B_ * HW_ * 1024;
  fp8_t* V8     = (fp8_t*)(ws + o); o += (size_t)B_ * C_ * HW_;
  fp8_t* hmT8   = (fp8_t*)(ws + o); o += (size_t)B_ * HW_ * C_;
  fp8_t* P8     = (fp8_t*)(ws + o); o += (size_t)B_ * HW_ * HW_;

  hipMemsetAsync(stats, 0, 128 * 2 * sizeof(float), stream);
  prep_kernel<<<2048, 256, 0, stream>>>(x, stats, qkv_w, proj_w, wqkv8, wproj8);
  norm_tr_kernel<<<dim3(HW_ / 64, C_ / 64, B_), 256, 0, stream>>>(x, stats, norm_w, norm_b, xnT8);
  qkv_gemm_kernel<<<1536, 256, 0, stream>>>(xnT8, wqkv8, qkv_b, QKt8, V8);
  sexp_gemm_kernel<<<4096, 256, 0, stream>>>(QKt8, P8);
  pv_gemm_kernel<<<512, 256, 0, stream>>>(P8, V8, hmT8);
  proj_gemm_kernel<<<dim3(HW_ / 128, C_ / 128, B_), 256, 0, stream>>>(
      wproj8, hmT8, proj_b, x, out);
}